// Round 19
// baseline (131.230 us; speedup 1.0000x reference)
//
#include <hip/hip_runtime.h>

#define NN 100000
#define NE 1600000
#define ET (NE + NN)      // logical edges incl. self-loops
#define NG 256
#define NEG_SLOPE 0.2f
#define SM_EPS 1e-16f

// ---- two-level bucketed CSR build ----
#define BSHIFT 7                       // bucket = dst >> 7 (128 nodes/bucket)
#define NBUCK ((NN + 127) / 128)       // 782
#define EPB 4096                       // edges per block in count/fill passes
#define NBLK ((ET + EPB - 1) / EPB)    // 416
#define MAXB 5120                      // LDS staging cap (max bucket ~2400)

typedef _Float16 half8 __attribute__((ext_vector_type(8)));

__device__ __forceinline__ float lrelu(float x) { return x > 0.0f ? x : NEG_SLOPE * x; }

__device__ __forceinline__ void edge_sd(const int* __restrict__ src,
                                        const int* __restrict__ dst,
                                        int e, int& s, int& d) {
    if (e < NE) { s = src[e]; d = dst[e]; } else { s = e - NE; d = s; }
}

// ---- A1: per-block per-bucket counts (dst only) ----
__global__ void k_countA(const int* __restrict__ dst, int* __restrict__ bcnt) {
    __shared__ int cnt[NBUCK];
    int t = threadIdx.x, bid = blockIdx.x;
    for (int i = t; i < NBUCK; i += 256) cnt[i] = 0;
    __syncthreads();
    int e0 = bid * EPB;
    #pragma unroll
    for (int k = 0; k < EPB / 256; ++k) {
        int e = e0 + k * 256 + t;
        if (e < ET) {
            int d = (e < NE) ? dst[e] : (e - NE);
            atomicAdd(&cnt[d >> BSHIFT], 1);
        }
    }
    __syncthreads();
    for (int i = t; i < NBUCK; i += 256) bcnt[i * NBLK + bid] = cnt[i];
}

// ---- A2a: per-bucket exclusive prefix over blocks ----
__global__ void k_scanrow(int* __restrict__ bcnt, int* __restrict__ gcnt) {
    int row = blockIdx.x, lane = threadIdx.x;   // 64 threads
    int running = 0;
    const int chunks = (NBLK + 63) / 64;
    for (int c = 0; c < chunks; ++c) {
        int i = c * 64 + lane;
        int v = (i < NBLK) ? bcnt[row * NBLK + i] : 0;
        int incl = v;
        #pragma unroll
        for (int o = 1; o < 64; o <<= 1) {
            int u = __shfl_up(incl, o, 64);
            if (lane >= o) incl += u;
        }
        if (i < NBLK) bcnt[row * NBLK + i] = running + (incl - v);
        running += __shfl(incl, 63, 64);
    }
    if (lane == 0) gcnt[row] = running;
}

// ---- A2b: exclusive scan of bucket totals + folded coefficients ----
__global__ void k_gscan(const int* __restrict__ gcnt, int* __restrict__ gbase,
                        const float* __restrict__ W1, const float* __restrict__ a1s,
                        const float* __restrict__ a1d,
                        const float* __restrict__ W2, const float* __restrict__ a2s,
                        const float* __restrict__ a2d,
                        float2* __restrict__ c12, float* __restrict__ c2s,
                        float* __restrict__ c2d) {
    __shared__ int sm[1024];
    int t = threadIdx.x;
    int v = (t < NBUCK) ? gcnt[t] : 0;
    sm[t] = v;
    if (t < 64) {
        float w  = (t < 32) ? W1[t] : 0.0f;
        float vs = (t < 32) ? w * a1s[t] : 0.0f;
        float vd = (t < 32) ? w * a1d[t] : 0.0f;
        #pragma unroll
        for (int o = 32; o; o >>= 1) {
            vs += __shfl_xor(vs, o, 64);
            vd += __shfl_xor(vd, o, 64);
        }
        if (t == 0) *c12 = make_float2(vs, vd);
    } else if (t < 96) {
        int k = t - 64;
        float s2 = 0.0f, d2 = 0.0f;
        for (int f = 0; f < 64; ++f) {
            float ww = W2[k * 64 + f];
            s2 += ww * a2s[f];
            d2 += ww * a2d[f];
        }
        c2s[k] = s2; c2d[k] = d2;
    }
    __syncthreads();
    for (int off = 1; off < 1024; off <<= 1) {
        int u = (t >= off) ? sm[t - off] : 0;
        __syncthreads();
        sm[t] += u;
        __syncthreads();
    }
    if (t < NBUCK) gbase[t] = sm[t] - v;
}

// ---- A3: fill compact bucket-major packed edge array ((s<<7)|(d&127)) ----
__global__ void k_fillA(const int* __restrict__ src, const int* __restrict__ dst,
                        const int* __restrict__ bcnt, const int* __restrict__ gbase,
                        int* __restrict__ bedge) {
    __shared__ int base[NBUCK];
    __shared__ int lcnt[NBUCK];
    int t = threadIdx.x, bid = blockIdx.x;
    for (int i = t; i < NBUCK; i += 256) {
        base[i] = gbase[i] + bcnt[i * NBLK + bid];
        lcnt[i] = 0;
    }
    __syncthreads();
    int e0 = bid * EPB;
    #pragma unroll
    for (int k = 0; k < EPB / 256; ++k) {
        int e = e0 + k * 256 + t;
        if (e < ET) {
            int s, d; edge_sd(src, dst, e, s, d);
            int b = d >> BSHIFT;
            int rank = atomicAdd(&lcnt[b], 1);
            bedge[base[b] + rank] = (s << 7) | (d & 127);
        }
    }
}

// ---- B: per-bucket LDS counting sort -> CSR + deg + row_start,
//      FUSED with layer-1 GAT + layer-2 pre (x2, ss, ds).
//      Block 0 also zeroes pooled/cnts for the downstream fused kernel.
__global__ void k_sortB(const int* __restrict__ gcnt, const int* __restrict__ gbase,
                        const int* __restrict__ bedge,
                        int* __restrict__ csr_src, int* __restrict__ deg,
                        int* __restrict__ row_start,
                        const float* __restrict__ x, const float2* __restrict__ c12,
                        const float* __restrict__ W1, const float* __restrict__ b1,
                        const float* __restrict__ c2s, const float* __restrict__ c2d,
                        _Float16* __restrict__ x2h,
                        float* __restrict__ ss, float* __restrict__ ds,
                        float* __restrict__ pooled, float* __restrict__ cnts) {
    __shared__ int lcnt[128], lstart[128], lcur[128];
    __shared__ int lout[MAXB];
    int b = blockIdx.x, t = threadIdx.x;        // 256 threads
    if (b == 0) {
        for (int i = t; i < NG * 64; i += 256) pooled[i] = 0.0f;
        for (int i = t; i < NG; i += 256) cnts[i] = 0.0f;
    }
    int cnt = gcnt[b];
    int base = gbase[b];
    const int* eb = bedge + base;
    if (t < 128) lcnt[t] = 0;
    __syncthreads();
    for (int i = t; i < cnt; i += 256)
        atomicAdd(&lcnt[eb[i] & 127], 1);
    __syncthreads();
    if (t < 128) lstart[t] = lcnt[t];
    __syncthreads();
    for (int off = 1; off < 128; off <<= 1) {
        int v = (t >= off && t < 128) ? lstart[t - off] : 0;
        __syncthreads();
        if (t < 128) lstart[t] += v;
        __syncthreads();
    }
    if (t < 128) {
        lstart[t] -= lcnt[t];          // exclusive
        lcur[t] = lstart[t];
    }
    __syncthreads();
    for (int i = t; i < cnt; i += 256) {
        int p = eb[i];
        int pos = atomicAdd(&lcur[p & 127], 1);
        lout[pos] = p >> 7;
    }
    __syncthreads();
    // coalesced CSR write + per-node metadata
    for (int i = t; i < cnt; i += 256)
        csr_src[base + i] = lout[i];
    if (t < 128) {
        int n = (b << BSHIFT) + t;
        if (n < NN) {
            deg[n] = lcnt[t];
            row_start[n] = base + lstart[t];
        }
    }
    // ---- fused layer 1 + layer-2 pre (pair of lanes per node) ----
    int i = t >> 1, half = t & 1;
    int n = (b << BSHIFT) + i;
    if (n >= NN) return;                        // pair-uniform exit
    float2 c = *c12;
    float xd = x[n];
    int st = lstart[i], cdeg = lcnt[i];
    float evs = 0.0f, wy = 0.0f;
    for (int j = half; j < cdeg; j += 2) {
        float xs = x[lout[st + j]];
        float ev = __expf(lrelu(c.x * xs + c.y * xd));
        evs += ev; wy += ev * xs;
    }
    evs += __shfl_xor(evs, 1, 64);
    wy  += __shfl_xor(wy, 1, 64);
    float y = wy / (evs + SM_EPS);
    int k0 = half * 16;
    half8 r0, r1;
    float vs = 0.0f, vd = 0.0f;
    #pragma unroll
    for (int k = 0; k < 8; ++k) {
        float xv = y * W1[k0 + k] + b1[k0 + k];
        xv = xv > 0.0f ? xv : 0.0f;
        r0[k] = (_Float16)xv;
        vs += xv * c2s[k0 + k]; vd += xv * c2d[k0 + k];
    }
    #pragma unroll
    for (int k = 0; k < 8; ++k) {
        float xv = y * W1[k0 + 8 + k] + b1[k0 + 8 + k];
        xv = xv > 0.0f ? xv : 0.0f;
        r1[k] = (_Float16)xv;
        vs += xv * c2s[k0 + 8 + k]; vd += xv * c2d[k0 + 8 + k];
    }
    half8* xp = (half8*)&x2h[(size_t)n * 32 + k0];
    xp[0] = r0; xp[1] = r1;
    vs += __shfl_xor(vs, 1, 64);
    vd += __shfl_xor(vd, 1, 64);
    if (half == 0) { ss[n] = vs; ds[n] = vd; }
}

// ---- layer 2 GAT + post-projection + relu + segmented pool, fully fused ----
// Block = 1024 threads = 64 nodes (16 lanes/node gather phase).
// Phase 1: per-node softmax-weighted x2 aggregate -> zs (LDS).
// Phase 2 (first 256 threads): OUT = relu(zs @ W2 + b2) pooled per graph.
__global__ void k_gat2pp(const int* __restrict__ row_start, const int* __restrict__ deg,
                         const int* __restrict__ csr_src,
                         const float* __restrict__ ss, const float* __restrict__ ds,
                         const half8* __restrict__ x2h,
                         const float* __restrict__ W2, const float* __restrict__ b2,
                         const int* __restrict__ batch,
                         float* __restrict__ pooled, float* __restrict__ cnts) {
    __shared__ float w2s[32 * 64];
    __shared__ float zs[64 * 32];
    int t = threadIdx.x;
    int n0 = blockIdx.x << 6;
    for (int i = t; i < 32 * 64; i += 1024) w2s[i] = W2[i];

    // ---- phase 1: gather/aggregate (16 lanes per node) ----
    int i64 = t >> 4;                   // node-local 0..63
    int sub = t & 15;
    int wid = n0 + i64;
    if (wid < NN) {
        int start = row_start[wid];
        int dg = deg[wid];
        float dsv = ds[wid];
        int eg = sub >> 2;              // edge subgroup 0..3
        int f8 = sub & 3;               // half8 index within 32 features
        float acc[8] = {0, 0, 0, 0, 0, 0, 0, 0};
        float evs = 0.0f;
        for (int i = eg; i < dg; i += 4) {
            int s = csr_src[start + i];          // broadcast within 4-lane subgroup
            float ev = __expf(lrelu(ss[s] + dsv));
            half8 hv = x2h[(size_t)s * 4 + f8];
            evs += ev;
            #pragma unroll
            for (int j = 0; j < 8; ++j) acc[j] += ev * (float)hv[j];
        }
        #pragma unroll
        for (int o = 4; o < 16; o <<= 1) {       // reduce across the 4 subgroups
            evs += __shfl_xor(evs, o, 64);
            #pragma unroll
            for (int j = 0; j < 8; ++j) acc[j] += __shfl_xor(acc[j], o, 64);
        }
        if (sub < 4) {
            float inv = 1.0f / (evs + SM_EPS);
            float4* dstp = (float4*)&zs[i64 * 32 + sub * 8];
            dstp[0] = make_float4(acc[0] * inv, acc[1] * inv, acc[2] * inv, acc[3] * inv);
            dstp[1] = make_float4(acc[4] * inv, acc[5] * inv, acc[6] * inv, acc[7] * inv);
        }
    }
    __syncthreads();

    // ---- phase 2: post-projection + pool (first 256 threads = 4 waves) ----
    if (t >= 256) return;
    int w = t >> 6, f = t & 63;
    int nw0 = n0 + w * 16;
    if (nw0 >= NN) return;                      // wave-uniform
    int n1 = nw0 + 16; if (n1 > NN) n1 = NN;
    float bv = b2[f];
    int curg = batch[nw0];
    float acc = 0.0f;
    int cnt = 0;
    for (int n = nw0; n < n1; ++n) {
        int g = batch[n];                       // wave-uniform
        if (g != curg) {
            atomicAdd(&pooled[curg * 64 + f], acc);
            if (f == 0) atomicAdd(&cnts[curg], (float)cnt);
            acc = 0.0f; cnt = 0; curg = g;
        }
        const float* zr = &zs[(n - n0) * 32];   // wave-uniform row -> broadcast
        float v = bv;
        #pragma unroll
        for (int k = 0; k < 32; ++k) v += zr[k] * w2s[k * 64 + f];
        acc += v > 0.0f ? v : 0.0f;
        ++cnt;
    }
    atomicAdd(&pooled[curg * 64 + f], acc);
    if (f == 0) atomicAdd(&cnts[curg], (float)cnt);
}

__global__ void k7_fc(const float* __restrict__ pooled, const float* __restrict__ cnts,
                      const float* __restrict__ fcW, const float* __restrict__ fcb,
                      float* __restrict__ out) {
    int g = threadIdx.x;
    if (g >= NG) return;
    float c = fmaxf(cnts[g], 1.0f);
    float o0 = fcb[0], o1 = fcb[1];
    for (int f = 0; f < 64; ++f) {
        float p = pooled[g * 64 + f] / c;
        o0 += p * fcW[f * 2 + 0];
        o1 += p * fcW[f * 2 + 1];
    }
    out[g * 2 + 0] = o0;
    out[g * 2 + 1] = o1;
}

extern "C" void kernel_launch(void* const* d_in, const int* in_sizes, int n_in,
                              void* d_out, int out_size, void* d_ws, size_t ws_size,
                              hipStream_t stream) {
    const float* x    = (const float*)d_in[0];
    const int*   ei   = (const int*)d_in[1];
    const int*   src  = ei;
    const int*   dst  = ei + NE;
    const int*   batch= (const int*)d_in[2];
    const float* W1   = (const float*)d_in[3];
    const float* a1s  = (const float*)d_in[4];
    const float* a1d  = (const float*)d_in[5];
    const float* b1   = (const float*)d_in[6];
    const float* W2   = (const float*)d_in[7];
    const float* a2s  = (const float*)d_in[8];
    const float* a2d  = (const float*)d_in[9];
    const float* b2   = (const float*)d_in[10];
    const float* fcW  = (const float*)d_in[11];
    const float* fcb  = (const float*)d_in[12];
    float* out = (float*)d_out;

    int* deg       = (int*)d_ws;                 // NN
    int* row_start = deg + NN;                   // NN
    int* csr_src   = row_start + NN;             // ET
    _Float16* x2h  = (_Float16*)(csr_src + ET);  // NN*32 halves (16B-aligned)
    int*   bedge   = (int*)(x2h + (size_t)NN * 32);  // ET
    float* scoreS  = (float*)(bedge + ET);       // NN
    float* scoreD  = scoreS + NN;                // NN
    float2* c12    = (float2*)(scoreD + NN);     // 1 float2
    float* c2s     = (float*)(c12 + 1);          // 32
    float* c2d     = c2s + 32;                   // 32
    float* pooled  = c2d + 32;                   // NG*64
    float* cnts    = pooled + NG * 64;           // NG
    int*   bcnt    = (int*)(cnts + NG);          // NBUCK*NBLK
    int*   gcnt    = bcnt + NBUCK * NBLK;        // NBUCK
    int*   gbase   = gcnt + NBUCK;               // NBUCK

    const int B = 256;

    // ---- CSR build: two-level LDS counting sort, zero global atomics ----
    k_countA<<<NBLK, B, 0, stream>>>(dst, bcnt);
    k_scanrow<<<NBUCK, 64, 0, stream>>>(bcnt, gcnt);
    k_gscan<<<1, 1024, 0, stream>>>(gcnt, gbase, W1, a1s, a1d, W2, a2s, a2d,
                                    c12, c2s, c2d);
    k_fillA<<<NBLK, B, 0, stream>>>(src, dst, bcnt, gbase, bedge);

    // ---- sort + layer 1 + layer-2 pre, fused (also zeroes pooled/cnts) ----
    k_sortB<<<NBUCK, B, 0, stream>>>(gcnt, gbase, bedge, csr_src, deg, row_start,
                                     x, c12, W1, b1, c2s, c2d,
                                     x2h, scoreS, scoreD, pooled, cnts);

    // ---- layer 2 GAT + post-projection + pool, fused ----
    int gridG = (NN + 63) / 64;
    k_gat2pp<<<gridG, 1024, 0, stream>>>(row_start, deg, csr_src,
                                         scoreS, scoreD, (const half8*)x2h,
                                         W2, b2, batch, pooled, cnts);

    // ---- fc ----
    k7_fc<<<1, B, 0, stream>>>(pooled, cnts, fcW, fcb, out);
}

// Round 20
// 120.488 us; speedup vs baseline: 1.0892x; 1.0892x over previous
//
#include <hip/hip_runtime.h>

#define NN 100000
#define NE 1600000
#define ET (NE + NN)      // logical edges incl. self-loops
#define NG 256
#define NEG_SLOPE 0.2f
#define SM_EPS 1e-16f

// ---- two-level bucketed CSR build ----
#define BSHIFT 7                       // bucket = dst >> 7 (128 nodes/bucket)
#define NBUCK ((NN + 127) / 128)       // 782
#define EPB 8192                       // edges per block in count/fill passes
#define NBLK ((ET + EPB - 1) / EPB)    // 208
#define MAXB 5120                      // LDS staging cap (max bucket ~2400)

typedef _Float16 half8 __attribute__((ext_vector_type(8)));

__device__ __forceinline__ float lrelu(float x) { return x > 0.0f ? x : NEG_SLOPE * x; }

__device__ __forceinline__ void edge_sd(const int* __restrict__ src,
                                        const int* __restrict__ dst,
                                        int e, int& s, int& d) {
    if (e < NE) { s = src[e]; d = dst[e]; } else { s = e - NE; d = s; }
}

// ---- A1: per-block per-bucket counts (dst only) ----
__global__ void k_countA(const int* __restrict__ dst, int* __restrict__ bcnt) {
    __shared__ int cnt[NBUCK];
    int t = threadIdx.x, bid = blockIdx.x;
    for (int i = t; i < NBUCK; i += 256) cnt[i] = 0;
    __syncthreads();
    int e0 = bid * EPB;
    #pragma unroll
    for (int k = 0; k < EPB / 256; ++k) {
        int e = e0 + k * 256 + t;
        if (e < ET) {
            int d = (e < NE) ? dst[e] : (e - NE);
            atomicAdd(&cnt[d >> BSHIFT], 1);
        }
    }
    __syncthreads();
    for (int i = t; i < NBUCK; i += 256) bcnt[i * NBLK + bid] = cnt[i];
}

// ---- A2a: per-bucket exclusive prefix over blocks ----
__global__ void k_scanrow(int* __restrict__ bcnt, int* __restrict__ gcnt) {
    int row = blockIdx.x, lane = threadIdx.x;   // 64 threads
    int running = 0;
    const int chunks = (NBLK + 63) / 64;
    for (int c = 0; c < chunks; ++c) {
        int i = c * 64 + lane;
        int v = (i < NBLK) ? bcnt[row * NBLK + i] : 0;
        int incl = v;
        #pragma unroll
        for (int o = 1; o < 64; o <<= 1) {
            int u = __shfl_up(incl, o, 64);
            if (lane >= o) incl += u;
        }
        if (i < NBLK) bcnt[row * NBLK + i] = running + (incl - v);
        running += __shfl(incl, 63, 64);
    }
    if (lane == 0) gcnt[row] = running;
}

// ---- A2b: exclusive scan of bucket totals + folded coefficients ----
__global__ void k_gscan(const int* __restrict__ gcnt, int* __restrict__ gbase,
                        const float* __restrict__ W1, const float* __restrict__ a1s,
                        const float* __restrict__ a1d,
                        const float* __restrict__ W2, const float* __restrict__ a2s,
                        const float* __restrict__ a2d,
                        float2* __restrict__ c12, float* __restrict__ c2s,
                        float* __restrict__ c2d) {
    __shared__ int sm[1024];
    int t = threadIdx.x;
    int v = (t < NBUCK) ? gcnt[t] : 0;
    sm[t] = v;
    if (t < 64) {
        float w  = (t < 32) ? W1[t] : 0.0f;
        float vs = (t < 32) ? w * a1s[t] : 0.0f;
        float vd = (t < 32) ? w * a1d[t] : 0.0f;
        #pragma unroll
        for (int o = 32; o; o >>= 1) {
            vs += __shfl_xor(vs, o, 64);
            vd += __shfl_xor(vd, o, 64);
        }
        if (t == 0) *c12 = make_float2(vs, vd);
    } else if (t < 96) {
        int k = t - 64;
        float s2 = 0.0f, d2 = 0.0f;
        for (int f = 0; f < 64; ++f) {
            float ww = W2[k * 64 + f];
            s2 += ww * a2s[f];
            d2 += ww * a2d[f];
        }
        c2s[k] = s2; c2d[k] = d2;
    }
    __syncthreads();
    for (int off = 1; off < 1024; off <<= 1) {
        int u = (t >= off) ? sm[t - off] : 0;
        __syncthreads();
        sm[t] += u;
        __syncthreads();
    }
    if (t < NBUCK) gbase[t] = sm[t] - v;
}

// ---- A3: fill compact bucket-major packed edge array ((s<<7)|(d&127)) ----
__global__ void k_fillA(const int* __restrict__ src, const int* __restrict__ dst,
                        const int* __restrict__ bcnt, const int* __restrict__ gbase,
                        int* __restrict__ bedge) {
    __shared__ int base[NBUCK];
    __shared__ int lcnt[NBUCK];
    int t = threadIdx.x, bid = blockIdx.x;
    for (int i = t; i < NBUCK; i += 256) {
        base[i] = gbase[i] + bcnt[i * NBLK + bid];
        lcnt[i] = 0;
    }
    __syncthreads();
    int e0 = bid * EPB;
    #pragma unroll
    for (int k = 0; k < EPB / 256; ++k) {
        int e = e0 + k * 256 + t;
        if (e < ET) {
            int s, d; edge_sd(src, dst, e, s, d);
            int b = d >> BSHIFT;
            int rank = atomicAdd(&lcnt[b], 1);
            bedge[base[b] + rank] = (s << 7) | (d & 127);
        }
    }
}

// ---- B: per-bucket LDS counting sort -> CSR + deg + row_start,
//      FUSED with layer-1 GAT + layer-2 pre (x2, ss, ds).
__global__ void k_sortB(const int* __restrict__ gcnt, const int* __restrict__ gbase,
                        const int* __restrict__ bedge,
                        int* __restrict__ csr_src, int* __restrict__ deg,
                        int* __restrict__ row_start,
                        const float* __restrict__ x, const float2* __restrict__ c12,
                        const float* __restrict__ W1, const float* __restrict__ b1,
                        const float* __restrict__ c2s, const float* __restrict__ c2d,
                        _Float16* __restrict__ x2h,
                        float* __restrict__ ss, float* __restrict__ ds) {
    __shared__ int lcnt[128], lstart[128], lcur[128];
    __shared__ int lout[MAXB];
    int b = blockIdx.x, t = threadIdx.x;        // 256 threads
    int cnt = gcnt[b];
    int base = gbase[b];
    const int* eb = bedge + base;
    if (t < 128) lcnt[t] = 0;
    __syncthreads();
    for (int i = t; i < cnt; i += 256)
        atomicAdd(&lcnt[eb[i] & 127], 1);
    __syncthreads();
    if (t < 128) lstart[t] = lcnt[t];
    __syncthreads();
    for (int off = 1; off < 128; off <<= 1) {
        int v = (t >= off && t < 128) ? lstart[t - off] : 0;
        __syncthreads();
        if (t < 128) lstart[t] += v;
        __syncthreads();
    }
    if (t < 128) {
        lstart[t] -= lcnt[t];          // exclusive
        lcur[t] = lstart[t];
    }
    __syncthreads();
    for (int i = t; i < cnt; i += 256) {
        int p = eb[i];
        int pos = atomicAdd(&lcur[p & 127], 1);
        lout[pos] = p >> 7;
    }
    __syncthreads();
    // coalesced CSR write + per-node metadata
    for (int i = t; i < cnt; i += 256)
        csr_src[base + i] = lout[i];
    if (t < 128) {
        int n = (b << BSHIFT) + t;
        if (n < NN) {
            deg[n] = lcnt[t];
            row_start[n] = base + lstart[t];
        }
    }
    // ---- fused layer 1 + layer-2 pre (pair of lanes per node) ----
    int i = t >> 1, half = t & 1;
    int n = (b << BSHIFT) + i;
    if (n >= NN) return;                        // pair-uniform exit
    float2 c = *c12;
    float xd = x[n];
    int st = lstart[i], cdeg = lcnt[i];
    float evs = 0.0f, wy = 0.0f;
    for (int j = half; j < cdeg; j += 2) {
        float xs = x[lout[st + j]];
        float ev = __expf(lrelu(c.x * xs + c.y * xd));
        evs += ev; wy += ev * xs;
    }
    evs += __shfl_xor(evs, 1, 64);
    wy  += __shfl_xor(wy, 1, 64);
    float y = wy / (evs + SM_EPS);
    int k0 = half * 16;
    half8 r0, r1;
    float vs = 0.0f, vd = 0.0f;
    #pragma unroll
    for (int k = 0; k < 8; ++k) {
        float xv = y * W1[k0 + k] + b1[k0 + k];
        xv = xv > 0.0f ? xv : 0.0f;
        r0[k] = (_Float16)xv;
        vs += xv * c2s[k0 + k]; vd += xv * c2d[k0 + k];
    }
    #pragma unroll
    for (int k = 0; k < 8; ++k) {
        float xv = y * W1[k0 + 8 + k] + b1[k0 + 8 + k];
        xv = xv > 0.0f ? xv : 0.0f;
        r1[k] = (_Float16)xv;
        vs += xv * c2s[k0 + 8 + k]; vd += xv * c2d[k0 + 8 + k];
    }
    half8* xp = (half8*)&x2h[(size_t)n * 32 + k0];
    xp[0] = r0; xp[1] = r1;
    vs += __shfl_xor(vs, 1, 64);
    vd += __shfl_xor(vd, 1, 64);
    if (half == 0) { ss[n] = vs; ds[n] = vd; }
}

// ---- layer 2 GAT: 16 lanes per node (4 nodes/wave), single pass, no-max.
// Block 0 also zeroes pooled/cnts for the downstream fused pool kernel.
__global__ void k_gat2(const int* __restrict__ row_start, const int* __restrict__ deg,
                       const int* __restrict__ csr_src,
                       const float* __restrict__ ss, const float* __restrict__ ds,
                       const half8* __restrict__ x2h, float* __restrict__ Z,
                       float* __restrict__ pooled, float* __restrict__ cnts) {
    if (blockIdx.x == 0) {
        int t = threadIdx.x;
        for (int i = t; i < NG * 64; i += 256) pooled[i] = 0.0f;
        for (int i = t; i < NG; i += 256) cnts[i] = 0.0f;
    }
    int wid = (blockIdx.x * blockDim.x + threadIdx.x) >> 4;
    int sub = threadIdx.x & 15;
    if (wid >= NN) return;
    int start = row_start[wid];
    int dg = deg[wid];
    float dsv = ds[wid];

    int eg = sub >> 2;                  // edge subgroup 0..3
    int f8 = sub & 3;                   // half8 index within 32 features
    float acc[8] = {0, 0, 0, 0, 0, 0, 0, 0};
    float evs = 0.0f;
    for (int i = eg; i < dg; i += 4) {
        int s = csr_src[start + i];              // broadcast within 4-lane subgroup
        float ev = __expf(lrelu(ss[s] + dsv));
        half8 hv = x2h[(size_t)s * 4 + f8];
        evs += ev;
        #pragma unroll
        for (int j = 0; j < 8; ++j) acc[j] += ev * (float)hv[j];
    }
    #pragma unroll
    for (int o = 4; o < 16; o <<= 1) {   // reduce across the 4 subgroups
        evs += __shfl_xor(evs, o, 64);
        #pragma unroll
        for (int j = 0; j < 8; ++j) acc[j] += __shfl_xor(acc[j], o, 64);
    }
    if (sub < 4) {
        float inv = 1.0f / (evs + SM_EPS);
        float4* dst = (float4*)&Z[(size_t)wid * 32 + sub * 8];
        dst[0] = make_float4(acc[0] * inv, acc[1] * inv, acc[2] * inv, acc[3] * inv);
        dst[1] = make_float4(acc[4] * inv, acc[5] * inv, acc[6] * inv, acc[7] * inv);
    }
}

// ---- fused post-projection + relu + segmented pool ----
// Block = 256 threads = 64 nodes. Z rows staged in LDS (coalesced); wave w
// computes nodes [w*16,(w+1)*16): lane = feature, zs reads broadcast, w2s
// conflict-free; segmented accumulate with graph-boundary flush atomics.
__global__ void k_post_pool(const float* __restrict__ Z, const float* __restrict__ W2,
                            const float* __restrict__ b2,
                            const int* __restrict__ batch,
                            float* __restrict__ pooled, float* __restrict__ cnts) {
    __shared__ float w2s[32 * 64];
    __shared__ float zs[64 * 32];
    int t = threadIdx.x;
    int n0 = blockIdx.x << 6;
    for (int i = t; i < 32 * 64; i += 256) w2s[i] = W2[i];
    for (int i = t; i < 64 * 32; i += 256) {
        int zi = n0 * 32 + i;
        zs[i] = (zi < NN * 32) ? Z[zi] : 0.0f;
    }
    __syncthreads();
    int w = t >> 6, f = t & 63;
    int nw0 = n0 + w * 16;
    if (nw0 >= NN) return;                      // wave-uniform
    int n1 = nw0 + 16; if (n1 > NN) n1 = NN;
    float bv = b2[f];
    int curg = batch[nw0];
    float acc = 0.0f;
    int cnt = 0;
    for (int n = nw0; n < n1; ++n) {
        int g = batch[n];                       // wave-uniform
        if (g != curg) {
            atomicAdd(&pooled[curg * 64 + f], acc);
            if (f == 0) atomicAdd(&cnts[curg], (float)cnt);
            acc = 0.0f; cnt = 0; curg = g;
        }
        const float* zr = &zs[(n - n0) * 32];   // wave-uniform row -> broadcast
        float v = bv;
        #pragma unroll
        for (int k = 0; k < 32; ++k) v += zr[k] * w2s[k * 64 + f];
        acc += v > 0.0f ? v : 0.0f;
        ++cnt;
    }
    atomicAdd(&pooled[curg * 64 + f], acc);
    if (f == 0) atomicAdd(&cnts[curg], (float)cnt);
}

// ---- fc: one wave per graph, lane = feature, butterfly reduce ----
__global__ void k7_fc(const float* __restrict__ pooled, const float* __restrict__ cnts,
                      const float* __restrict__ fcW, const float* __restrict__ fcb,
                      float* __restrict__ out) {
    int idx = blockIdx.x * blockDim.x + threadIdx.x;
    int g = idx >> 6, f = idx & 63;
    if (g >= NG) return;
    float c = fmaxf(cnts[g], 1.0f);
    float p = pooled[g * 64 + f] / c;            // coalesced row load
    float o0 = p * fcW[f * 2 + 0];
    float o1 = p * fcW[f * 2 + 1];
    #pragma unroll
    for (int o = 32; o; o >>= 1) {
        o0 += __shfl_xor(o0, o, 64);
        o1 += __shfl_xor(o1, o, 64);
    }
    if (f == 0) {
        out[g * 2 + 0] = o0 + fcb[0];
        out[g * 2 + 1] = o1 + fcb[1];
    }
}

extern "C" void kernel_launch(void* const* d_in, const int* in_sizes, int n_in,
                              void* d_out, int out_size, void* d_ws, size_t ws_size,
                              hipStream_t stream) {
    const float* x    = (const float*)d_in[0];
    const int*   ei   = (const int*)d_in[1];
    const int*   src  = ei;
    const int*   dst  = ei + NE;
    const int*   batch= (const int*)d_in[2];
    const float* W1   = (const float*)d_in[3];
    const float* a1s  = (const float*)d_in[4];
    const float* a1d  = (const float*)d_in[5];
    const float* b1   = (const float*)d_in[6];
    const float* W2   = (const float*)d_in[7];
    const float* a2s  = (const float*)d_in[8];
    const float* a2d  = (const float*)d_in[9];
    const float* b2   = (const float*)d_in[10];
    const float* fcW  = (const float*)d_in[11];
    const float* fcb  = (const float*)d_in[12];
    float* out = (float*)d_out;

    int* deg       = (int*)d_ws;                 // NN
    int* row_start = deg + NN;                   // NN
    int* csr_src   = row_start + NN;             // ET
    _Float16* x2h  = (_Float16*)(csr_src + ET);  // NN*32 halves (16B-aligned)
    float* Z       = (float*)(x2h + (size_t)NN * 32);  // NN*32 floats
    float* scoreS  = Z + (size_t)NN * 32;        // NN
    float* scoreD  = scoreS + NN;                // NN
    float2* c12    = (float2*)(scoreD + NN);     // 1 float2
    float* c2s     = (float*)(c12 + 1);          // 32
    float* c2d     = c2s + 32;                   // 32
    float* pooled  = c2d + 32;                   // NG*64
    float* cnts    = pooled + NG * 64;           // NG
    int*   bcnt    = (int*)(cnts + NG);          // NBUCK*NBLK
    int*   gcnt    = bcnt + NBUCK * NBLK;        // NBUCK
    int*   gbase   = gcnt + NBUCK;               // NBUCK
    int*   bedge   = (int*)Z;                    // alias: ET*4B = 6.8MB <= 12.8MB
                                                 // (dead before k_gat2 writes Z)

    const int B = 256;

    // ---- CSR build: two-level LDS counting sort, zero global atomics ----
    k_countA<<<NBLK, B, 0, stream>>>(dst, bcnt);
    k_scanrow<<<NBUCK, 64, 0, stream>>>(bcnt, gcnt);
    k_gscan<<<1, 1024, 0, stream>>>(gcnt, gbase, W1, a1s, a1d, W2, a2s, a2d,
                                    c12, c2s, c2d);
    k_fillA<<<NBLK, B, 0, stream>>>(src, dst, bcnt, gbase, bedge);

    // ---- sort + layer 1 + layer-2 pre, fused ----
    k_sortB<<<NBUCK, B, 0, stream>>>(gcnt, gbase, bedge, csr_src, deg, row_start,
                                     x, c12, W1, b1, c2s, c2d,
                                     x2h, scoreS, scoreD);

    // ---- layer 2 GAT (16 lanes/node, aggregate x2 -> Z; zeroes pooled) ----
    k_gat2<<<(NN * 16 + B - 1) / B, B, 0, stream>>>(row_start, deg, csr_src,
                                                    scoreS, scoreD,
                                                    (const half8*)x2h, Z,
                                                    pooled, cnts);

    // ---- fused post-projection + relu + pool, then fc ----
    int gridPP = (NN + 63) / 64;
    k_post_pool<<<gridPP, B, 0, stream>>>(Z, W2, b2, batch, pooled, cnts);
    k7_fc<<<(NG * 64 + B - 1) / B, B, 0, stream>>>(pooled, cnts, fcW, fcb, out);
}